// Round 9
// baseline (129.300 us; speedup 1.0000x reference)
//
#include <hip/hip_runtime.h>
#include <hip/hip_bf16.h>

#define CIN    32
#define NPIX   4096   // 64*64 spatial positions
#define DIM    64     // attention channels
#define LOG2E  1.4426950408889634f

#if __has_builtin(__builtin_amdgcn_exp2f)
#define EXP2(x) __builtin_amdgcn_exp2f(x)
#else
#define EXP2(x) exp2f(x)
#endif

typedef float  f32x4  __attribute__((ext_vector_type(4)));
typedef float  f32x16 __attribute__((ext_vector_type(16)));
typedef short  s16x8  __attribute__((ext_vector_type(8)));   // 8 bf16 = one 32x32x16 A/B fragment

#define ZERO16 {0.f,0.f,0.f,0.f,0.f,0.f,0.f,0.f,0.f,0.f,0.f,0.f,0.f,0.f,0.f,0.f}

__device__ __forceinline__ f32x16 mfma32(s16x8 a, s16x8 b, f32x16 c) {
    return __builtin_amdgcn_mfma_f32_32x32x16_bf16(a, b, c, 0, 0, 0);
}

// ---------------------------------------------------------------------------
// Layouts (all per batch b):
//  Q: row-major (N, 64), PRE-SCALED by log2(e).
//  K: 32x32x16 A-frag order: [s(128)][kt(4)][h2(2)][key(32)][j(8)]
//     element = K[pixel s*32+key][dim kt*16 + h2*8 + j]   (4 KB per tile s)
//  V: CONTIGUOUS-frag order of V^T: [s(128)][cht(2)][m(2)][hk(2)][ch'(32)][j(8)]
//     element = V[key s*32 + 16m + (j&3) + 8*(j>>2) + 4*hk][ch cht*32+ch']
//     (frag (cht,m) is one contiguous 1 KB block; addr = lane*16 + j*2)
//  No softmax shift anywhere: scores' = s*log2e <= ~30, exp2 safe in f32/bf16.
// ---------------------------------------------------------------------------

// ---------------------------------------------------------------------------
// Kernel A: QKV projection. Q row-major (scaled); K/V in 32x32 frag orders.
// ---------------------------------------------------------------------------
__global__ __launch_bounds__(256) void qkv_proj(
    const float* __restrict__ x,
    const float* __restrict__ wq, const float* __restrict__ bq,
    const float* __restrict__ wk, const float* __restrict__ bk,
    const float* __restrict__ wv, const float* __restrict__ bv,
    __hip_bfloat16* __restrict__ qb, __hip_bfloat16* __restrict__ kb,
    __hip_bfloat16* __restrict__ vb)
{
    __shared__ float Xs[CIN][64];        // [c_in][pixel]
    __shared__ float wT[3][CIN][DIM];    // [mat][c_in][c_out]; wT[0] pre-scaled

    const int tid = threadIdx.x;
    const int b   = blockIdx.y;
    const int bx  = blockIdx.x;
    const int n0  = bx * 64;

    for (int i = tid; i < 3 * CIN * DIM; i += 256) {
        int m = i >> 11, r = i & 2047, c = r >> 6, o = r & 63;
        const float* wsrc = (m == 0) ? wq : (m == 1) ? wk : wv;
        float wv0 = wsrc[o * CIN + c];
        wT[m][c][o] = (m == 0) ? wv0 * LOG2E : wv0;
    }
    for (int i = tid * 4; i < CIN * 64; i += 1024) {
        int c = i >> 6, p = i & 63;
        *(f32x4*)&Xs[c][p] = *(const f32x4*)&x[((size_t)b * CIN + c) * NPIX + n0 + p];
    }
    __syncthreads();

    const int w    = tid >> 6;
    const int lane = tid & 63;
    const int l16  = lane >> 2;
    const int quad = lane & 3;

    const int T  = bx * 4 + w;
    const int px = T * 16 + l16;

    float aq[2][8], ak[2][8];
    #pragma unroll
    for (int kb2 = 0; kb2 < 2; kb2++) {
        f32x4 bq0 = *(const f32x4*)&bq[kb2 * 32 + quad * 8];
        f32x4 bq1 = *(const f32x4*)&bq[kb2 * 32 + quad * 8 + 4];
        f32x4 bk0 = *(const f32x4*)&bk[kb2 * 32 + quad * 8];
        f32x4 bk1 = *(const f32x4*)&bk[kb2 * 32 + quad * 8 + 4];
        #pragma unroll
        for (int j = 0; j < 4; j++) {
            aq[kb2][j] = bq0[j] * LOG2E; aq[kb2][j + 4] = bq1[j] * LOG2E;
            ak[kb2][j] = bk0[j];         ak[kb2][j + 4] = bk1[j];
        }
    }
    #pragma unroll 8
    for (int c = 0; c < CIN; c++) {
        const float xc = Xs[c][w * 16 + l16];
        #pragma unroll
        for (int kb2 = 0; kb2 < 2; kb2++) {
            f32x4 q0 = *(const f32x4*)&wT[0][c][kb2 * 32 + quad * 8];
            f32x4 q1 = *(const f32x4*)&wT[0][c][kb2 * 32 + quad * 8 + 4];
            f32x4 k0 = *(const f32x4*)&wT[1][c][kb2 * 32 + quad * 8];
            f32x4 k1 = *(const f32x4*)&wT[1][c][kb2 * 32 + quad * 8 + 4];
            #pragma unroll
            for (int j = 0; j < 4; j++) {
                aq[kb2][j]     += xc * q0[j];
                aq[kb2][j + 4] += xc * q1[j];
                ak[kb2][j]     += xc * k0[j];
                ak[kb2][j + 4] += xc * k1[j];
            }
        }
    }
    // Q store row-major; K store in 32x32 A-frag order.
    {
        const int s   = px >> 5;
        const int key = px & 31;
        #pragma unroll
        for (int kb2 = 0; kb2 < 2; kb2++) {
            union { s16x8 v; __hip_bfloat16 h[8]; } pq, pk;
            #pragma unroll
            for (int j = 0; j < 8; j++) {
                pq.h[j] = __float2bfloat16(aq[kb2][j]);
                pk.h[j] = __float2bfloat16(ak[kb2][j]);
            }
            *(s16x8*)(qb + ((size_t)b * NPIX + px) * DIM + kb2 * 32 + quad * 8) = pq.v;
            const int kt = kb2 * 2 + (quad >> 1);
            const int h  = quad & 1;
            const size_t koff = (size_t)b * 262144
                + ((size_t)(s * 4 + kt) * 64 + h * 32 + key) * 8;
            *(s16x8*)(kb + koff) = pk.v;
        }
    }

    const int ch = w * 16 + l16;
    float av[2][8];
    {
        const float bvc = bv[ch];
        #pragma unroll
        for (int kh = 0; kh < 2; kh++)
            #pragma unroll
            for (int j = 0; j < 8; j++) av[kh][j] = bvc;
    }
    #pragma unroll 8
    for (int c = 0; c < CIN; c++) {
        const float wvc = wT[2][c][ch];
        f32x4 x0 = *(const f32x4*)&Xs[c][quad * 8];
        f32x4 x1 = *(const f32x4*)&Xs[c][quad * 8 + 4];
        f32x4 x2 = *(const f32x4*)&Xs[c][32 + quad * 8];
        f32x4 x3 = *(const f32x4*)&Xs[c][32 + quad * 8 + 4];
        #pragma unroll
        for (int j = 0; j < 4; j++) {
            av[0][j]     += x0[j] * wvc;
            av[0][j + 4] += x1[j] * wvc;
            av[1][j]     += x2[j] * wvc;
            av[1][j + 4] += x3[j] * wvc;
        }
    }
    // av[kh][jj] = V[key quad*8+jj (tile s=bx*2+kh)][ch].  Emit contiguous
    // frag order: kappa = quad*8+jj -> m = quad>>1, hk = jj>>2,
    // j' = (jj&3) + 4*(quad&1).
    #pragma unroll
    for (int kh = 0; kh < 2; kh++) {
        const int s = bx * 2 + kh;
        #pragma unroll
        for (int h = 0; h < 2; h++) {
            union { unsigned long long u; __hip_bfloat16 hh[4]; } pv;
            #pragma unroll
            for (int j = 0; j < 4; j++) pv.hh[j] = __float2bfloat16(av[kh][h * 4 + j]);
            const size_t voff = (size_t)b * 262144
                + (size_t)(s * 4 + (ch >> 5) * 2 + (quad >> 1)) * 512
                + (size_t)(h * 32 + (ch & 31)) * 8
                + 4 * (quad & 1);
            *(unsigned long long*)(vb + voff) = pv.u;
        }
    }
}

// ---------------------------------------------------------------------------
// Kernel B v8 (resubmit; R8 was an infra failure, no counters returned):
//   v7 structure + 2 BLOCKS/CU (4 waves/SIMD).
//   - REDx epilogue partials ALIASED into the 64 KB staging buffer (only
//     used after the loop; all loop-phase LDS readers have arrived at the
//     final barrier before any epilogue write). LDS 99.8 -> 66 KB.
//   - __launch_bounds__(512,4): <=128 unified regs. Live-range diet:
//     V frags ds_read AFTER exp2/pack (kf+s dead); staging loads issued
//     after S cluster, ds_written after PV. Peak ~121 regs by audit.
//   - Spill guard: FETCH_SIZE must stay ~8.3 MB / WRITE_SIZE 4 MB.
// ---------------------------------------------------------------------------
__global__ __launch_bounds__(512, 4) void attn_fused(
    const __hip_bfloat16* __restrict__ qb,
    const __hip_bfloat16* __restrict__ kbf,
    const __hip_bfloat16* __restrict__ vbf,
    const float* __restrict__ wo, const float* __restrict__ bo,
    const float* __restrict__ x, float* __restrict__ y)
{
    __shared__ __align__(16) char sm[2][8][4096];   // 64 KB staging; epilogue aliases
    __shared__ float LRED2[4][32];                  // row-sums 512 B

    float (*REDx)[64][33] = (float (*)[64][33])&sm[0][0][0];   // 33792 B alias

    const int tid  = threadIdx.x;
    const int w    = tid >> 6;          // wave 0..7
    const int g    = w >> 1;            // q-group (32 rows)
    const int h    = w & 1;             // key half (2048 keys = 32 phases x 2 tiles)
    const int lane = tid & 63;
    const int q    = lane & 31;         // C/D column = q-row index
    const int hl   = lane >> 5;         // lane half
    const int b    = blockIdx.x;        // batch -> XCD affinity (lin%8 = b)
    const int row0 = blockIdx.y * 128 + g * 32;

    // Q B-frags (32x32x16): elem j at half hl -> dim kt*16 + hl*8 + j
    s16x8 qf[4];
    #pragma unroll
    for (int kt = 0; kt < 4; kt++)
        qf[kt] = *(const s16x8*)(qb + ((size_t)b * NPIX + row0 + q) * DIM
                                 + kt * 16 + hl * 8);

    f32x16 o0 = ZERO16, o1 = ZERO16;    // O^T[ch 0-31][q], O^T[ch 32-63][q]
    float lsacc = 0.f;                  // per-lane partial row-sum

    // staging: wave w stages one full 4 KB tile/phase, slot w.
    //   w = kv(1)|half_s(1)|sub(1):  kv = w>>2, half_s = (w>>1)&1, sub = w&1
    const char* stbase = ((w >> 2) ? (const char*)vbf : (const char*)kbf)
                       + (size_t)b * 524288
                       + (size_t)((w >> 1) & 1) * 262144    // 64 tiles per key-half
                       + (size_t)(w & 1) * 4096
                       + (size_t)lane * 16;
    char* std0 = &sm[0][w][lane * 16];
    char* std1 = &sm[1][w][lane * 16];

    // prologue: stage phase 0 into buf 0
    #pragma unroll
    for (int i = 0; i < 4; i++)
        *(f32x4*)(std0 + i * 1024) = *(const f32x4*)(stbase + i * 1024);
    __syncthreads();

    int cur = 0;
    for (int p = 0; p < 32; ++p) {
        // K fragments from current buffer (stride-16: conflict-free)
        const char* K0 = sm[cur][h * 2 + 0];
        const char* K1 = sm[cur][h * 2 + 1];
        s16x8 kf0[4], kf1[4];
        #pragma unroll
        for (int i = 0; i < 4; i++) {
            kf0[i] = *(const s16x8*)(K0 + i * 1024 + lane * 16);
            kf1[i] = *(const s16x8*)(K1 + i * 1024 + lane * 16);
        }

        // S^T per tile: one 4-deep chain each; two independent chains feed pipe
        __builtin_amdgcn_s_setprio(1);
        f32x16 s0 = ZERO16, s1 = ZERO16;
        s0 = mfma32(kf0[0], qf[0], s0);
        s1 = mfma32(kf1[0], qf[0], s1);
        s0 = mfma32(kf0[1], qf[1], s0);
        s1 = mfma32(kf1[1], qf[1], s1);
        s0 = mfma32(kf0[2], qf[2], s0);
        s1 = mfma32(kf1[2], qf[2], s1);
        s0 = mfma32(kf0[3], qf[3], s0);
        s1 = mfma32(kf1[3], qf[3], s1);
        __builtin_amdgcn_s_setprio(0);

        // issue next-phase global loads (latency hides under exp2/pack + PV)
        const size_t srcoff = (size_t)((p < 31) ? p + 1 : 31) * 8192;
        f32x4 r0 = *(const f32x4*)(stbase + srcoff);
        f32x4 r1 = *(const f32x4*)(stbase + srcoff + 1024);
        f32x4 r2 = *(const f32x4*)(stbase + srcoff + 2048);
        f32x4 r3 = *(const f32x4*)(stbase + srcoff + 3072);

        // P^T = exp2(S^T) -> bf16 B-frags; VALU row-sum (kf, s die here)
        union { s16x8 v; __hip_bfloat16 h8[8]; } p00, p01, p10, p11;
        #pragma unroll
        for (int r = 0; r < 16; r++) { s0[r] = EXP2(s0[r]); lsacc += s0[r]; }
        #pragma unroll
        for (int j = 0; j < 8; j++) {
            p00.h8[j] = __float2bfloat16(s0[j]);
            p01.h8[j] = __float2bfloat16(s0[8 + j]);
        }
        #pragma unroll
        for (int r = 0; r < 16; r++) { s1[r] = EXP2(s1[r]); lsacc += s1[r]; }
        #pragma unroll
        for (int j = 0; j < 8; j++) {
            p10.h8[j] = __float2bfloat16(s1[j]);
            p11.h8[j] = __float2bfloat16(s1[8 + j]);
        }

        // V fragments (read late: kf/s regs already free)
        const char* V0 = sm[cur][4 + h * 2 + 0];
        const char* V1 = sm[cur][4 + h * 2 + 1];
        s16x8 vv0[4], vv1[4];
        #pragma unroll
        for (int i = 0; i < 4; i++) {
            vv0[i] = *(const s16x8*)(V0 + i * 1024 + lane * 16);
            vv1[i] = *(const s16x8*)(V1 + i * 1024 + lane * 16);
        }

        // O^T += V^T P^T  (8 MFMAs, two 4-deep accum chains)
        __builtin_amdgcn_s_setprio(1);
        o0 = mfma32(vv0[0], p00.v, o0);
        o1 = mfma32(vv0[2], p00.v, o1);
        o0 = mfma32(vv0[1], p01.v, o0);
        o1 = mfma32(vv0[3], p01.v, o1);
        o0 = mfma32(vv1[0], p10.v, o0);
        o1 = mfma32(vv1[2], p10.v, o1);
        o0 = mfma32(vv1[1], p11.v, o0);
        o1 = mfma32(vv1[3], p11.v, o1);
        __builtin_amdgcn_s_setprio(0);

        // write staged tile into the other buffer, then phase barrier
        char* dst = cur ? std0 : std1;
        *(f32x4*)(dst)        = r0;
        *(f32x4*)(dst + 1024) = r1;
        *(f32x4*)(dst + 2048) = r2;
        *(f32x4*)(dst + 3072) = r3;
        __syncthreads();
        cur ^= 1;
    }

    // cross-half row-sum combine (both lane-halves hold same q, disjoint keys)
    lsacc += __shfl_xor(lsacc, 32, 64);

    // ---- combine the two key-halves per q-group (REDx aliases staging) ----
    if (h == 1) {
        #pragma unroll
        for (int i = 0; i < 16; i++) {
            const int rr = (i & 3) + 8 * (i >> 2) + 4 * hl;
            REDx[g][rr][q]      = o0[i];
            REDx[g][32 + rr][q] = o1[i];
        }
        if (hl == 0) LRED2[g][q] = lsacc;
    }
    __syncthreads();

    if (h == 0) {
        const float lsum = lsacc + LRED2[g][q];
        #pragma unroll
        for (int i = 0; i < 16; i++) {
            const int rr = (i & 3) + 8 * (i >> 2) + 4 * hl;
            o0[i] += REDx[g][rr][q];
            o1[i] += REDx[g][32 + rr][q];
        }
        const float inv = 1.0f / lsum;

        // normalized O^T -> B-frags per 16-ch group (direct from registers)
        s16x8 pbo[4];
        #pragma unroll
        for (int gg = 0; gg < 4; gg++) {
            union { s16x8 v; __hip_bfloat16 h8[8]; } pk;
            #pragma unroll
            for (int j = 0; j < 8; j++) {
                const float vv = (gg < 2) ? o0[(gg & 1) * 8 + j] : o1[(gg & 1) * 8 + j];
                pk.h8[j] = __float2bfloat16(vv * inv);
            }
            pbo[gg] = pk.v;
        }

        // wo A-frags with the key/ch relabeling mu(gg,hl,j)
        s16x8 aw[4];
        #pragma unroll
        for (int gg = 0; gg < 4; gg++) {
            f32x4 w0 = *(const f32x4*)(wo + (size_t)q * DIM + gg * 16 + hl * 4);
            f32x4 w1 = *(const f32x4*)(wo + (size_t)q * DIM + gg * 16 + 8 + hl * 4);
            union { s16x8 v; __hip_bfloat16 h8[8]; } wf;
            #pragma unroll
            for (int j = 0; j < 4; j++) {
                wf.h8[j]     = __float2bfloat16(w0[j]);
                wf.h8[4 + j] = __float2bfloat16(w1[j]);
            }
            aw[gg] = wf.v;
        }

        // Y^T[out][q] = wo x ONorm^T  (single 32x32 tile, K=64 over 4 mfmas)
        f32x16 d = ZERO16;
        #pragma unroll
        for (int gg = 0; gg < 4; gg++)
            d = mfma32(aw[gg], pbo[gg], d);

        // bias + residual + store y (B, 32, 4096) fp32
        #pragma unroll
        for (int i = 0; i < 16; i++) {
            const int out = (i & 3) + 8 * (i >> 2) + 4 * hl;
            const int row = row0 + q;
            const size_t xi = ((size_t)b * CIN + out) * NPIX + row;
            y[xi] = d[i] + bo[out] + x[xi];
        }
    }
}

// ---------------------------------------------------------------------------
extern "C" void kernel_launch(void* const* d_in, const int* in_sizes, int n_in,
                              void* d_out, int out_size, void* d_ws, size_t ws_size,
                              hipStream_t stream)
{
    const float* x  = (const float*)d_in[0];
    const float* wq = (const float*)d_in[1];
    const float* bq = (const float*)d_in[2];
    const float* wk = (const float*)d_in[3];
    const float* bk = (const float*)d_in[4];
    const float* wv = (const float*)d_in[5];
    const float* bv = (const float*)d_in[6];
    const float* wo = (const float*)d_in[7];
    const float* bo = (const float*)d_in[8];
    float* y = (float*)d_out;

    // workspace: qb 4MB (row-major, log2e-scaled) | kb 4MB | vb 4MB (frag orders)
    char* ws = (char*)d_ws;
    __hip_bfloat16* qb = (__hip_bfloat16*)(ws);
    __hip_bfloat16* kb = (__hip_bfloat16*)(ws + (4u << 20));
    __hip_bfloat16* vb = (__hip_bfloat16*)(ws + (8u << 20));

    qkv_proj<<<dim3(64, 8), dim3(256), 0, stream>>>(x, wq, bq, wk, bk, wv, bv, qb, kb, vb);
    attn_fused<<<dim3(8, 32), dim3(512), 0, stream>>>(qb, kb, vb, wo, bo, x, y);
}